// Round 10
// baseline (980.988 us; speedup 1.0000x reference)
//
#include <hip/hip_runtime.h>
#include <cstdint>

// GNNEncoder: 2-layer GCN, N=100000 nodes, E=1.6M edges, D=H=128, f32.
// Pipeline per launch (all state rebuilt each call):
//   memset counts -> hist(dst) -> scan(offsets,cursor,dis) -> scatter(CSR src)
//   -> GEMM1 (x@W1 -> Hws) -> agg1 (+self,+b1, leakyrelu, threefry dropout -> d_out)
//   -> GEMM2 (d_out@W2 -> Hws) -> agg2 (+self,+b2 -> d_out)
// Dropout mask VARIANT C: JAX partitionable path, counter (hi=0, lo=i),
// 32-bit random bits = bits1 ^ bits2 (XOR fold per _threefry_random_bits_partitionable).
// Falsified: A (o1) r4=0.157; D (original split-half) r7=0.140; B (o0) r8=0.175.

#define CH 128  // channels (D == H == 128)

// ---------------- JAX threefry2x32 (standard 20-round) ----------------
__device__ __forceinline__ uint32_t rotl32(uint32_t v, int r) {
  return (v << r) | (v >> (32 - r));
}

__device__ __forceinline__ void threefry2x32(uint32_t k0, uint32_t k1,
                                             uint32_t x0, uint32_t x1,
                                             uint32_t& o0, uint32_t& o1) {
  const uint32_t ks2 = k0 ^ k1 ^ 0x1BD11BDAu;
  x0 += k0; x1 += k1;
  // group 1: rotations {13,15,26,6}
  x0 += x1; x1 = rotl32(x1, 13); x1 ^= x0;
  x0 += x1; x1 = rotl32(x1, 15); x1 ^= x0;
  x0 += x1; x1 = rotl32(x1, 26); x1 ^= x0;
  x0 += x1; x1 = rotl32(x1,  6); x1 ^= x0;
  x0 += k1; x1 += ks2 + 1u;
  // group 2: rotations {17,29,16,24}
  x0 += x1; x1 = rotl32(x1, 17); x1 ^= x0;
  x0 += x1; x1 = rotl32(x1, 29); x1 ^= x0;
  x0 += x1; x1 = rotl32(x1, 16); x1 ^= x0;
  x0 += x1; x1 = rotl32(x1, 24); x1 ^= x0;
  x0 += ks2; x1 += k0 + 2u;
  // group 3
  x0 += x1; x1 = rotl32(x1, 13); x1 ^= x0;
  x0 += x1; x1 = rotl32(x1, 15); x1 ^= x0;
  x0 += x1; x1 = rotl32(x1, 26); x1 ^= x0;
  x0 += x1; x1 = rotl32(x1,  6); x1 ^= x0;
  x0 += k0; x1 += k1 + 3u;
  // group 4
  x0 += x1; x1 = rotl32(x1, 17); x1 ^= x0;
  x0 += x1; x1 = rotl32(x1, 29); x1 ^= x0;
  x0 += x1; x1 = rotl32(x1, 16); x1 ^= x0;
  x0 += x1; x1 = rotl32(x1, 24); x1 ^= x0;
  x0 += k1; x1 += ks2 + 4u;
  // group 5
  x0 += x1; x1 = rotl32(x1, 13); x1 ^= x0;
  x0 += x1; x1 = rotl32(x1, 15); x1 ^= x0;
  x0 += x1; x1 = rotl32(x1, 26); x1 ^= x0;
  x0 += x1; x1 = rotl32(x1,  6); x1 ^= x0;
  x0 += ks2; x1 += k0 + 5u;
  o0 = x0; o1 = x1;
}

// VARIANT C: partitionable path, counter (hi=0, lo=i), bits = bits1 ^ bits2.
__device__ __forceinline__ bool keep_mask(uint32_t i) {
  uint32_t o0, o1;
  threefry2x32(0u, 42u, 0u, i, o0, o1);
  const uint32_t bits = o0 ^ o1;
  float u = __uint_as_float((bits >> 9) | 0x3f800000u) - 1.0f;
  return u < 0.9f;
}

// ---------------- graph prep ----------------
__global__ void k_hist(const int* __restrict__ ei, int* __restrict__ cnt, int E) {
  int e = blockIdx.x * blockDim.x + threadIdx.x;
  if (e < E) {
    int dst = ei[E + e];
    atomicAdd(&cnt[dst], 1);
  }
}

__global__ __launch_bounds__(1024) void k_scan(const int* __restrict__ cnt,
                                               int* __restrict__ offs,
                                               int* __restrict__ cursor,
                                               float* __restrict__ dis, int n) {
  __shared__ int part[1024];
  const int t = threadIdx.x;
  const int chunk = (n + 1023) / 1024;
  int start = t * chunk;
  int end = min(start + chunk, n);
  int s = 0;
  for (int i = start; i < end; ++i) s += cnt[i];
  part[t] = s;
  __syncthreads();
  for (int d = 1; d < 1024; d <<= 1) {
    int v = (t >= d) ? part[t - d] : 0;
    __syncthreads();
    part[t] += v;
    __syncthreads();
  }
  int run = (t == 0) ? 0 : part[t - 1];
  for (int i = start; i < end; ++i) {
    int c = cnt[i];
    offs[i] = run;
    cursor[i] = run;
    dis[i] = rsqrtf((float)c + 1.0f);  // deg includes self-loop
    run += c;
  }
  if (t == 1023) offs[n] = run;
}

__global__ void k_scatter(const int* __restrict__ ei, int* __restrict__ cursor,
                          int* __restrict__ csr, int E) {
  int e = blockIdx.x * blockDim.x + threadIdx.x;
  if (e < E) {
    int src = ei[e];
    int dst = ei[E + e];
    int p = atomicAdd(&cursor[dst], 1);
    csr[p] = src;
  }
}

// ---------------- f32 GEMM: [M,128] x [128,128], 64x64 tile, 4x4 reg tile ----
__global__ __launch_bounds__(256) void k_gemm(const float* __restrict__ A,
                                              const float* __restrict__ B,
                                              float* __restrict__ C, int M) {
  __shared__ float As[64][132];   // +4 pad: column reads spread over banks
  __shared__ float Bs[128][68];   // +4 keeps float4 rows 16B-aligned
  const int tid = threadIdx.x;
  const int rowBase = blockIdx.x * 64;
  const int colBase = blockIdx.y * 64;

  #pragma unroll
  for (int i = 0; i < 8; ++i) {           // A tile: 64 rows x 128 cols
    int f = tid + i * 256;                // 2048 float4
    int r = f >> 5;
    int c4 = (f & 31) << 2;
    int gr = rowBase + r;
    float4 v = make_float4(0.f, 0.f, 0.f, 0.f);
    if (gr < M) v = *reinterpret_cast<const float4*>(&A[(size_t)gr * CH + c4]);
    As[r][c4 + 0] = v.x; As[r][c4 + 1] = v.y; As[r][c4 + 2] = v.z; As[r][c4 + 3] = v.w;
  }
  #pragma unroll
  for (int i = 0; i < 8; ++i) {           // B tile: 128 k x 64 cols
    int f = tid + i * 256;
    int r = f >> 4;
    int c4 = (f & 15) << 2;
    float4 v = *reinterpret_cast<const float4*>(&B[r * CH + colBase + c4]);
    Bs[r][c4 + 0] = v.x; Bs[r][c4 + 1] = v.y; Bs[r][c4 + 2] = v.z; Bs[r][c4 + 3] = v.w;
  }
  __syncthreads();

  const int tx = tid & 15, ty = tid >> 4;
  const int r0 = ty * 4, c0 = tx * 4;
  float acc[4][4] = {};
  #pragma unroll 4
  for (int k = 0; k < 128; ++k) {
    float a0 = As[r0 + 0][k], a1 = As[r0 + 1][k], a2 = As[r0 + 2][k], a3 = As[r0 + 3][k];
    float4 b = *reinterpret_cast<const float4*>(&Bs[k][c0]);
    acc[0][0] += a0 * b.x; acc[0][1] += a0 * b.y; acc[0][2] += a0 * b.z; acc[0][3] += a0 * b.w;
    acc[1][0] += a1 * b.x; acc[1][1] += a1 * b.y; acc[1][2] += a1 * b.z; acc[1][3] += a1 * b.w;
    acc[2][0] += a2 * b.x; acc[2][1] += a2 * b.y; acc[2][2] += a2 * b.z; acc[2][3] += a2 * b.w;
    acc[3][0] += a3 * b.x; acc[3][1] += a3 * b.y; acc[3][2] += a3 * b.z; acc[3][3] += a3 * b.w;
  }
  #pragma unroll
  for (int i = 0; i < 4; ++i) {
    int gr = rowBase + r0 + i;
    if (gr < M) {
      float4 v = make_float4(acc[i][0], acc[i][1], acc[i][2], acc[i][3]);
      *reinterpret_cast<float4*>(&C[(size_t)gr * CH + colBase + c0]) = v;
    }
  }
}

// ---------------- aggregation: 1 wave per dst node, lane = 2 channels --------
template <int LAYER>
__global__ __launch_bounds__(256) void k_agg(const float* __restrict__ H,
                                             const int* __restrict__ offs,
                                             const int* __restrict__ csr,
                                             const float* __restrict__ dis,
                                             const float* __restrict__ bias,
                                             float* __restrict__ out, int n) {
  int wid = (blockIdx.x * 256 + threadIdx.x) >> 6;
  int lane = threadIdx.x & 63;
  if (wid >= n) return;
  const int row = wid;
  const float dd = dis[row];
  int e = offs[row];
  const int end = offs[row + 1];
  const int c = lane * 2;
  float ax0 = 0.f, ay0 = 0.f, ax1 = 0.f, ay1 = 0.f;
  for (; e + 1 < end; e += 2) {           // unroll-2: two independent load chains
    int s0 = csr[e], s1 = csr[e + 1];
    float n0 = dis[s0] * dd, n1 = dis[s1] * dd;
    float2 v0 = *reinterpret_cast<const float2*>(&H[(size_t)s0 * CH + c]);
    float2 v1 = *reinterpret_cast<const float2*>(&H[(size_t)s1 * CH + c]);
    ax0 += v0.x * n0; ay0 += v0.y * n0;
    ax1 += v1.x * n1; ay1 += v1.y * n1;
  }
  if (e < end) {
    int s0 = csr[e];
    float n0 = dis[s0] * dd;
    float2 v0 = *reinterpret_cast<const float2*>(&H[(size_t)s0 * CH + c]);
    ax0 += v0.x * n0; ay0 += v0.y * n0;
  }
  float2 vs = *reinterpret_cast<const float2*>(&H[(size_t)row * CH + c]);
  float ax = ax0 + ax1 + vs.x * dd * dd + bias[c];
  float ay = ay0 + ay1 + vs.y * dd * dd + bias[c + 1];
  if (LAYER == 1) {
    ax = ax > 0.f ? ax : 0.01f * ax;      // leaky_relu(0.01)
    ay = ay > 0.f ? ay : 0.01f * ay;
    uint32_t i0 = (uint32_t)row * (uint32_t)CH + (uint32_t)c;
    ax = keep_mask(i0)      ? ax * (1.0f / 0.9f) : 0.0f;
    ay = keep_mask(i0 + 1u) ? ay * (1.0f / 0.9f) : 0.0f;
  }
  float2 o; o.x = ax; o.y = ay;
  *reinterpret_cast<float2*>(&out[(size_t)row * CH + c]) = o;
}

// ---------------- launch ----------------
extern "C" void kernel_launch(void* const* d_in, const int* in_sizes, int n_in,
                              void* d_out, int out_size, void* d_ws, size_t ws_size,
                              hipStream_t stream) {
  const float* x = (const float*)d_in[0];
  const int* ei = (const int*)d_in[1];   // int32 per harness contract, [2, E]
  const float* W1 = (const float*)d_in[2];
  const float* b1 = (const float*)d_in[3];
  const float* W2 = (const float*)d_in[4];
  const float* b2 = (const float*)d_in[5];
  float* out = (float*)d_out;

  const int N = in_sizes[0] / CH;     // 100000
  const int E = in_sizes[1] / 2;      // 1600000

  // workspace carve-up (256B aligned), total ~59.2 MB
  char* ws = (char*)d_ws;
  size_t o = 0;
  auto take = [&](size_t bytes) -> void* {
    void* p = ws + o;
    o = (o + bytes + 255) & ~(size_t)255;
    return p;
  };
  int* cnt    = (int*)take((size_t)N * 4);
  int* offs   = (int*)take((size_t)(N + 1) * 4);
  int* cursor = (int*)take((size_t)N * 4);
  float* dis  = (float*)take((size_t)N * 4);
  int* csr    = (int*)take((size_t)E * 4);
  float* Hws  = (float*)take((size_t)N * CH * 4);

  hipMemsetAsync(cnt, 0, (size_t)N * 4, stream);

  const int eb = (E + 255) / 256;
  k_hist<<<eb, 256, 0, stream>>>(ei, cnt, E);
  k_scan<<<1, 1024, 0, stream>>>(cnt, offs, cursor, dis, N);
  k_scatter<<<eb, 256, 0, stream>>>(ei, cursor, csr, E);

  dim3 gg((N + 63) / 64, CH / 64);
  const int ab = (N + 3) / 4;                               // 4 waves/block
  k_gemm<<<gg, 256, 0, stream>>>(x, W1, Hws, N);            // Hws = x @ W1
  k_agg<1><<<ab, 256, 0, stream>>>(Hws, offs, csr, dis, b1, out, N);
  k_gemm<<<gg, 256, 0, stream>>>(out, W2, Hws, N);          // Hws = H2 @ W2
  k_agg<2><<<ab, 256, 0, stream>>>(Hws, offs, csr, dis, b2, out, N);
}

// Round 11
// 700.222 us; speedup vs baseline: 1.4010x; 1.4010x over previous
//
#include <hip/hip_runtime.h>
#include <cstdint>

// GNNEncoder: 2-layer GCN, N=100000 nodes, E=1.6M edges, D=H=128, f32.
// r10: PASSED (981 us). Dropout = VARIANT C: partitionable threefry, counter
// (hi=0, lo=i), bits = o0 ^ o1 (XOR fold). DO NOT TOUCH keep_mask.
// r11 change: single-block k_scan (284 us, occupancy 0.14%) -> 3-kernel
// hierarchical scan (k_scan1/2/3, ~10-15 us predicted).

#define CH 128  // channels (D == H == 128)

// ---------------- JAX threefry2x32 (standard 20-round) ----------------
__device__ __forceinline__ uint32_t rotl32(uint32_t v, int r) {
  return (v << r) | (v >> (32 - r));
}

__device__ __forceinline__ void threefry2x32(uint32_t k0, uint32_t k1,
                                             uint32_t x0, uint32_t x1,
                                             uint32_t& o0, uint32_t& o1) {
  const uint32_t ks2 = k0 ^ k1 ^ 0x1BD11BDAu;
  x0 += k0; x1 += k1;
  // group 1: rotations {13,15,26,6}
  x0 += x1; x1 = rotl32(x1, 13); x1 ^= x0;
  x0 += x1; x1 = rotl32(x1, 15); x1 ^= x0;
  x0 += x1; x1 = rotl32(x1, 26); x1 ^= x0;
  x0 += x1; x1 = rotl32(x1,  6); x1 ^= x0;
  x0 += k1; x1 += ks2 + 1u;
  // group 2: rotations {17,29,16,24}
  x0 += x1; x1 = rotl32(x1, 17); x1 ^= x0;
  x0 += x1; x1 = rotl32(x1, 29); x1 ^= x0;
  x0 += x1; x1 = rotl32(x1, 16); x1 ^= x0;
  x0 += x1; x1 = rotl32(x1, 24); x1 ^= x0;
  x0 += ks2; x1 += k0 + 2u;
  // group 3
  x0 += x1; x1 = rotl32(x1, 13); x1 ^= x0;
  x0 += x1; x1 = rotl32(x1, 15); x1 ^= x0;
  x0 += x1; x1 = rotl32(x1, 26); x1 ^= x0;
  x0 += x1; x1 = rotl32(x1,  6); x1 ^= x0;
  x0 += k0; x1 += k1 + 3u;
  // group 4
  x0 += x1; x1 = rotl32(x1, 17); x1 ^= x0;
  x0 += x1; x1 = rotl32(x1, 29); x1 ^= x0;
  x0 += x1; x1 = rotl32(x1, 16); x1 ^= x0;
  x0 += x1; x1 = rotl32(x1, 24); x1 ^= x0;
  x0 += k1; x1 += ks2 + 4u;
  // group 5
  x0 += x1; x1 = rotl32(x1, 13); x1 ^= x0;
  x0 += x1; x1 = rotl32(x1, 15); x1 ^= x0;
  x0 += x1; x1 = rotl32(x1, 26); x1 ^= x0;
  x0 += x1; x1 = rotl32(x1,  6); x1 ^= x0;
  x0 += ks2; x1 += k0 + 5u;
  o0 = x0; o1 = x1;
}

// VARIANT C (verified r10): bits = o0 ^ o1, counter (hi=0, lo=i).
__device__ __forceinline__ bool keep_mask(uint32_t i) {
  uint32_t o0, o1;
  threefry2x32(0u, 42u, 0u, i, o0, o1);
  const uint32_t bits = o0 ^ o1;
  float u = __uint_as_float((bits >> 9) | 0x3f800000u) - 1.0f;
  return u < 0.9f;
}

// ---------------- graph prep ----------------
__global__ void k_hist(const int* __restrict__ ei, int* __restrict__ cnt, int E) {
  int e = blockIdx.x * blockDim.x + threadIdx.x;
  if (e < E) {
    int dst = ei[E + e];
    atomicAdd(&cnt[dst], 1);
  }
}

// Hierarchical prefix sum over cnt[0..n): 1024 elements per block, 256 threads.
__global__ __launch_bounds__(256) void k_scan1(const int* __restrict__ cnt,
                                               int* __restrict__ bsum, int n) {
  const int tid = threadIdx.x;
  const int i0 = blockIdx.x * 1024 + tid * 4;
  int s = 0;
  if (i0 + 3 < n) {
    int4 v = *reinterpret_cast<const int4*>(&cnt[i0]);
    s = v.x + v.y + v.z + v.w;
  } else {
    for (int k = 0; k < 4; ++k) if (i0 + k < n) s += cnt[i0 + k];
  }
  __shared__ int red[256];
  red[tid] = s;
  __syncthreads();
  for (int d = 128; d > 0; d >>= 1) {
    if (tid < d) red[tid] += red[tid + d];
    __syncthreads();
  }
  if (tid == 0) bsum[blockIdx.x] = red[0];
}

// Exclusive scan of nb block sums (nb ~ 98), single block, carry loop for nb>128.
__global__ __launch_bounds__(128) void k_scan2(const int* __restrict__ bsum,
                                               int* __restrict__ bpre, int nb) {
  __shared__ int sh[128];
  const int t = threadIdx.x;
  int carry = 0;
  for (int base = 0; base < nb; base += 128) {
    int v = (base + t < nb) ? bsum[base + t] : 0;
    sh[t] = v;
    __syncthreads();
    for (int d = 1; d < 128; d <<= 1) {
      int u = (t >= d) ? sh[t - d] : 0;
      __syncthreads();
      sh[t] += u;
      __syncthreads();
    }
    if (base + t < nb) bpre[base + t] = carry + sh[t] - v;  // exclusive
    carry += sh[127];
    __syncthreads();
  }
}

// Final: intra-block exclusive scan + block offset -> offs/cursor/dis.
__global__ __launch_bounds__(256) void k_scan3(const int* __restrict__ cnt,
                                               const int* __restrict__ bpre,
                                               int* __restrict__ offs,
                                               int* __restrict__ cursor,
                                               float* __restrict__ dis,
                                               int n, int Etot) {
  const int tid = threadIdx.x;
  const int i0 = blockIdx.x * 1024 + tid * 4;
  int c0 = 0, c1 = 0, c2 = 0, c3 = 0;
  if (i0 + 3 < n) {
    int4 v = *reinterpret_cast<const int4*>(&cnt[i0]);
    c0 = v.x; c1 = v.y; c2 = v.z; c3 = v.w;
  } else {
    if (i0 + 0 < n) c0 = cnt[i0 + 0];
    if (i0 + 1 < n) c1 = cnt[i0 + 1];
    if (i0 + 2 < n) c2 = cnt[i0 + 2];
    if (i0 + 3 < n) c3 = cnt[i0 + 3];
  }
  const int s = c0 + c1 + c2 + c3;
  __shared__ int sh[256];
  sh[tid] = s;
  __syncthreads();
  for (int d = 1; d < 256; d <<= 1) {
    int u = (tid >= d) ? sh[tid - d] : 0;
    __syncthreads();
    sh[tid] += u;
    __syncthreads();
  }
  int pre = bpre[blockIdx.x] + sh[tid] - s;  // exclusive within grid
  int cc[4] = {c0, c1, c2, c3};
  #pragma unroll
  for (int k = 0; k < 4; ++k) {
    int i = i0 + k;
    if (i < n) {
      offs[i] = pre;
      cursor[i] = pre;
      dis[i] = rsqrtf((float)cc[k] + 1.0f);  // deg includes self-loop
      pre += cc[k];
    }
  }
  if (blockIdx.x == 0 && tid == 0) offs[n] = Etot;  // sum(cnt) == E exactly
}

__global__ void k_scatter(const int* __restrict__ ei, int* __restrict__ cursor,
                          int* __restrict__ csr, int E) {
  int e = blockIdx.x * blockDim.x + threadIdx.x;
  if (e < E) {
    int src = ei[e];
    int dst = ei[E + e];
    int p = atomicAdd(&cursor[dst], 1);
    csr[p] = src;
  }
}

// ---------------- f32 GEMM: [M,128] x [128,128], 64x64 tile, 4x4 reg tile ----
__global__ __launch_bounds__(256) void k_gemm(const float* __restrict__ A,
                                              const float* __restrict__ B,
                                              float* __restrict__ C, int M) {
  __shared__ float As[64][132];   // +4 pad: column reads spread over banks
  __shared__ float Bs[128][68];   // +4 keeps float4 rows 16B-aligned
  const int tid = threadIdx.x;
  const int rowBase = blockIdx.x * 64;
  const int colBase = blockIdx.y * 64;

  #pragma unroll
  for (int i = 0; i < 8; ++i) {           // A tile: 64 rows x 128 cols
    int f = tid + i * 256;                // 2048 float4
    int r = f >> 5;
    int c4 = (f & 31) << 2;
    int gr = rowBase + r;
    float4 v = make_float4(0.f, 0.f, 0.f, 0.f);
    if (gr < M) v = *reinterpret_cast<const float4*>(&A[(size_t)gr * CH + c4]);
    As[r][c4 + 0] = v.x; As[r][c4 + 1] = v.y; As[r][c4 + 2] = v.z; As[r][c4 + 3] = v.w;
  }
  #pragma unroll
  for (int i = 0; i < 8; ++i) {           // B tile: 128 k x 64 cols
    int f = tid + i * 256;
    int r = f >> 4;
    int c4 = (f & 15) << 2;
    float4 v = *reinterpret_cast<const float4*>(&B[r * CH + colBase + c4]);
    Bs[r][c4 + 0] = v.x; Bs[r][c4 + 1] = v.y; Bs[r][c4 + 2] = v.z; Bs[r][c4 + 3] = v.w;
  }
  __syncthreads();

  const int tx = tid & 15, ty = tid >> 4;
  const int r0 = ty * 4, c0 = tx * 4;
  float acc[4][4] = {};
  #pragma unroll 4
  for (int k = 0; k < 128; ++k) {
    float a0 = As[r0 + 0][k], a1 = As[r0 + 1][k], a2 = As[r0 + 2][k], a3 = As[r0 + 3][k];
    float4 b = *reinterpret_cast<const float4*>(&Bs[k][c0]);
    acc[0][0] += a0 * b.x; acc[0][1] += a0 * b.y; acc[0][2] += a0 * b.z; acc[0][3] += a0 * b.w;
    acc[1][0] += a1 * b.x; acc[1][1] += a1 * b.y; acc[1][2] += a1 * b.z; acc[1][3] += a1 * b.w;
    acc[2][0] += a2 * b.x; acc[2][1] += a2 * b.y; acc[2][2] += a2 * b.z; acc[2][3] += a2 * b.w;
    acc[3][0] += a3 * b.x; acc[3][1] += a3 * b.y; acc[3][2] += a3 * b.z; acc[3][3] += a3 * b.w;
  }
  #pragma unroll
  for (int i = 0; i < 4; ++i) {
    int gr = rowBase + r0 + i;
    if (gr < M) {
      float4 v = make_float4(acc[i][0], acc[i][1], acc[i][2], acc[i][3]);
      *reinterpret_cast<float4*>(&C[(size_t)gr * CH + colBase + c0]) = v;
    }
  }
}

// ---------------- aggregation: 1 wave per dst node, lane = 2 channels --------
template <int LAYER>
__global__ __launch_bounds__(256) void k_agg(const float* __restrict__ H,
                                             const int* __restrict__ offs,
                                             const int* __restrict__ csr,
                                             const float* __restrict__ dis,
                                             const float* __restrict__ bias,
                                             float* __restrict__ out, int n) {
  int wid = (blockIdx.x * 256 + threadIdx.x) >> 6;
  int lane = threadIdx.x & 63;
  if (wid >= n) return;
  const int row = wid;
  const float dd = dis[row];
  int e = offs[row];
  const int end = offs[row + 1];
  const int c = lane * 2;
  float ax0 = 0.f, ay0 = 0.f, ax1 = 0.f, ay1 = 0.f;
  for (; e + 1 < end; e += 2) {           // unroll-2: two independent load chains
    int s0 = csr[e], s1 = csr[e + 1];
    float n0 = dis[s0] * dd, n1 = dis[s1] * dd;
    float2 v0 = *reinterpret_cast<const float2*>(&H[(size_t)s0 * CH + c]);
    float2 v1 = *reinterpret_cast<const float2*>(&H[(size_t)s1 * CH + c]);
    ax0 += v0.x * n0; ay0 += v0.y * n0;
    ax1 += v1.x * n1; ay1 += v1.y * n1;
  }
  if (e < end) {
    int s0 = csr[e];
    float n0 = dis[s0] * dd;
    float2 v0 = *reinterpret_cast<const float2*>(&H[(size_t)s0 * CH + c]);
    ax0 += v0.x * n0; ay0 += v0.y * n0;
  }
  float2 vs = *reinterpret_cast<const float2*>(&H[(size_t)row * CH + c]);
  float ax = ax0 + ax1 + vs.x * dd * dd + bias[c];
  float ay = ay0 + ay1 + vs.y * dd * dd + bias[c + 1];
  if (LAYER == 1) {
    ax = ax > 0.f ? ax : 0.01f * ax;      // leaky_relu(0.01)
    ay = ay > 0.f ? ay : 0.01f * ay;
    uint32_t i0 = (uint32_t)row * (uint32_t)CH + (uint32_t)c;
    ax = keep_mask(i0)      ? ax * (1.0f / 0.9f) : 0.0f;
    ay = keep_mask(i0 + 1u) ? ay * (1.0f / 0.9f) : 0.0f;
  }
  float2 o; o.x = ax; o.y = ay;
  *reinterpret_cast<float2*>(&out[(size_t)row * CH + c]) = o;
}

// ---------------- launch ----------------
extern "C" void kernel_launch(void* const* d_in, const int* in_sizes, int n_in,
                              void* d_out, int out_size, void* d_ws, size_t ws_size,
                              hipStream_t stream) {
  const float* x = (const float*)d_in[0];
  const int* ei = (const int*)d_in[1];   // int32 per harness contract, [2, E]
  const float* W1 = (const float*)d_in[2];
  const float* b1 = (const float*)d_in[3];
  const float* W2 = (const float*)d_in[4];
  const float* b2 = (const float*)d_in[5];
  float* out = (float*)d_out;

  const int N = in_sizes[0] / CH;     // 100000
  const int E = in_sizes[1] / 2;      // 1600000
  const int nb = (N + 1023) / 1024;   // scan blocks (98)

  // workspace carve-up (256B aligned), total ~59.2 MB
  char* ws = (char*)d_ws;
  size_t o = 0;
  auto take = [&](size_t bytes) -> void* {
    void* p = ws + o;
    o = (o + bytes + 255) & ~(size_t)255;
    return p;
  };
  int* cnt    = (int*)take((size_t)N * 4);
  int* offs   = (int*)take((size_t)(N + 1) * 4);
  int* cursor = (int*)take((size_t)N * 4);
  float* dis  = (float*)take((size_t)N * 4);
  int* csr    = (int*)take((size_t)E * 4);
  int* bsum   = (int*)take((size_t)nb * 4);
  int* bpre   = (int*)take((size_t)nb * 4);
  float* Hws  = (float*)take((size_t)N * CH * 4);

  hipMemsetAsync(cnt, 0, (size_t)N * 4, stream);

  const int eb = (E + 255) / 256;
  k_hist<<<eb, 256, 0, stream>>>(ei, cnt, E);
  k_scan1<<<nb, 256, 0, stream>>>(cnt, bsum, N);
  k_scan2<<<1, 128, 0, stream>>>(bsum, bpre, nb);
  k_scan3<<<nb, 256, 0, stream>>>(cnt, bpre, offs, cursor, dis, N, E);
  k_scatter<<<eb, 256, 0, stream>>>(ei, cursor, csr, E);

  dim3 gg((N + 63) / 64, CH / 64);
  const int ab = (N + 3) / 4;                               // 4 waves/block
  k_gemm<<<gg, 256, 0, stream>>>(x, W1, Hws, N);            // Hws = x @ W1
  k_agg<1><<<ab, 256, 0, stream>>>(Hws, offs, csr, dis, b1, out, N);
  k_gemm<<<gg, 256, 0, stream>>>(out, W2, Hws, N);          // Hws = H2 @ W2
  k_agg<2><<<ab, 256, 0, stream>>>(Hws, offs, csr, dis, b2, out, N);
}

// Round 17
// 663.316 us; speedup vs baseline: 1.4789x; 1.0556x over previous
//
#include <hip/hip_runtime.h>
#include <cstdint>

// GNNEncoder: 2-layer GCN, N=100000 nodes, E=1.6M edges, D=H=128, f32.
// r10: PASSED 981us (dropout VARIANT C: partitionable threefry, counter (0,i),
//      bits = o0 ^ o1. DO NOT TOUCH keep_mask).
// r11: hierarchical scan -> 700us. k_agg now top (150us x2, latency-bound:
//      VALU 36%, 40% HBM, occ 75%).
// r12 change: (a) GEMM epilogue pre-scales rows by dis[row] (H' = (A@W)*dis),
//      so agg inner loop is pure adds with csr->H the only dependent chain;
//      (b) agg unrolled 4-deep (4 independent gather chains).
//      out = (sum_edges H'[src] + H'[row]) * dd + bias  (exact same f32 sum
//      up to reassociation; margin 5.5x).

#define CH 128  // channels (D == H == 128)

// ---------------- JAX threefry2x32 (standard 20-round) ----------------
__device__ __forceinline__ uint32_t rotl32(uint32_t v, int r) {
  return (v << r) | (v >> (32 - r));
}

__device__ __forceinline__ void threefry2x32(uint32_t k0, uint32_t k1,
                                             uint32_t x0, uint32_t x1,
                                             uint32_t& o0, uint32_t& o1) {
  const uint32_t ks2 = k0 ^ k1 ^ 0x1BD11BDAu;
  x0 += k0; x1 += k1;
  // group 1: rotations {13,15,26,6}
  x0 += x1; x1 = rotl32(x1, 13); x1 ^= x0;
  x0 += x1; x1 = rotl32(x1, 15); x1 ^= x0;
  x0 += x1; x1 = rotl32(x1, 26); x1 ^= x0;
  x0 += x1; x1 = rotl32(x1,  6); x1 ^= x0;
  x0 += k1; x1 += ks2 + 1u;
  // group 2: rotations {17,29,16,24}
  x0 += x1; x1 = rotl32(x1, 17); x1 ^= x0;
  x0 += x1; x1 = rotl32(x1, 29); x1 ^= x0;
  x0 += x1; x1 = rotl32(x1, 16); x1 ^= x0;
  x0 += x1; x1 = rotl32(x1, 24); x1 ^= x0;
  x0 += ks2; x1 += k0 + 2u;
  // group 3
  x0 += x1; x1 = rotl32(x1, 13); x1 ^= x0;
  x0 += x1; x1 = rotl32(x1, 15); x1 ^= x0;
  x0 += x1; x1 = rotl32(x1, 26); x1 ^= x0;
  x0 += x1; x1 = rotl32(x1,  6); x1 ^= x0;
  x0 += k0; x1 += k1 + 3u;
  // group 4
  x0 += x1; x1 = rotl32(x1, 17); x1 ^= x0;
  x0 += x1; x1 = rotl32(x1, 29); x1 ^= x0;
  x0 += x1; x1 = rotl32(x1, 16); x1 ^= x0;
  x0 += x1; x1 = rotl32(x1, 24); x1 ^= x0;
  x0 += k1; x1 += ks2 + 4u;
  // group 5
  x0 += x1; x1 = rotl32(x1, 13); x1 ^= x0;
  x0 += x1; x1 = rotl32(x1, 15); x1 ^= x0;
  x0 += x1; x1 = rotl32(x1, 26); x1 ^= x0;
  x0 += x1; x1 = rotl32(x1,  6); x1 ^= x0;
  x0 += ks2; x1 += k0 + 5u;
  o0 = x0; o1 = x1;
}

// VARIANT C (verified r10): bits = o0 ^ o1, counter (hi=0, lo=i).
__device__ __forceinline__ bool keep_mask(uint32_t i) {
  uint32_t o0, o1;
  threefry2x32(0u, 42u, 0u, i, o0, o1);
  const uint32_t bits = o0 ^ o1;
  float u = __uint_as_float((bits >> 9) | 0x3f800000u) - 1.0f;
  return u < 0.9f;
}

// ---------------- graph prep ----------------
__global__ void k_hist(const int* __restrict__ ei, int* __restrict__ cnt, int E) {
  int e = blockIdx.x * blockDim.x + threadIdx.x;
  if (e < E) {
    int dst = ei[E + e];
    atomicAdd(&cnt[dst], 1);
  }
}

// Hierarchical prefix sum over cnt[0..n): 1024 elements per block, 256 threads.
__global__ __launch_bounds__(256) void k_scan1(const int* __restrict__ cnt,
                                               int* __restrict__ bsum, int n) {
  const int tid = threadIdx.x;
  const int i0 = blockIdx.x * 1024 + tid * 4;
  int s = 0;
  if (i0 + 3 < n) {
    int4 v = *reinterpret_cast<const int4*>(&cnt[i0]);
    s = v.x + v.y + v.z + v.w;
  } else {
    for (int k = 0; k < 4; ++k) if (i0 + k < n) s += cnt[i0 + k];
  }
  __shared__ int red[256];
  red[tid] = s;
  __syncthreads();
  for (int d = 128; d > 0; d >>= 1) {
    if (tid < d) red[tid] += red[tid + d];
    __syncthreads();
  }
  if (tid == 0) bsum[blockIdx.x] = red[0];
}

// Exclusive scan of nb block sums (nb ~ 98), single block, carry loop for nb>128.
__global__ __launch_bounds__(128) void k_scan2(const int* __restrict__ bsum,
                                               int* __restrict__ bpre, int nb) {
  __shared__ int sh[128];
  const int t = threadIdx.x;
  int carry = 0;
  for (int base = 0; base < nb; base += 128) {
    int v = (base + t < nb) ? bsum[base + t] : 0;
    sh[t] = v;
    __syncthreads();
    for (int d = 1; d < 128; d <<= 1) {
      int u = (t >= d) ? sh[t - d] : 0;
      __syncthreads();
      sh[t] += u;
      __syncthreads();
    }
    if (base + t < nb) bpre[base + t] = carry + sh[t] - v;  // exclusive
    carry += sh[127];
    __syncthreads();
  }
}

// Final: intra-block exclusive scan + block offset -> offs/cursor/dis.
__global__ __launch_bounds__(256) void k_scan3(const int* __restrict__ cnt,
                                               const int* __restrict__ bpre,
                                               int* __restrict__ offs,
                                               int* __restrict__ cursor,
                                               float* __restrict__ dis,
                                               int n, int Etot) {
  const int tid = threadIdx.x;
  const int i0 = blockIdx.x * 1024 + tid * 4;
  int c0 = 0, c1 = 0, c2 = 0, c3 = 0;
  if (i0 + 3 < n) {
    int4 v = *reinterpret_cast<const int4*>(&cnt[i0]);
    c0 = v.x; c1 = v.y; c2 = v.z; c3 = v.w;
  } else {
    if (i0 + 0 < n) c0 = cnt[i0 + 0];
    if (i0 + 1 < n) c1 = cnt[i0 + 1];
    if (i0 + 2 < n) c2 = cnt[i0 + 2];
    if (i0 + 3 < n) c3 = cnt[i0 + 3];
  }
  const int s = c0 + c1 + c2 + c3;
  __shared__ int sh[256];
  sh[tid] = s;
  __syncthreads();
  for (int d = 1; d < 256; d <<= 1) {
    int u = (tid >= d) ? sh[tid - d] : 0;
    __syncthreads();
    sh[tid] += u;
    __syncthreads();
  }
  int pre = bpre[blockIdx.x] + sh[tid] - s;  // exclusive within grid
  int cc[4] = {c0, c1, c2, c3};
  #pragma unroll
  for (int k = 0; k < 4; ++k) {
    int i = i0 + k;
    if (i < n) {
      offs[i] = pre;
      cursor[i] = pre;
      dis[i] = rsqrtf((float)cc[k] + 1.0f);  // deg includes self-loop
      pre += cc[k];
    }
  }
  if (blockIdx.x == 0 && tid == 0) offs[n] = Etot;  // sum(cnt) == E exactly
}

__global__ void k_scatter(const int* __restrict__ ei, int* __restrict__ cursor,
                          int* __restrict__ csr, int E) {
  int e = blockIdx.x * blockDim.x + threadIdx.x;
  if (e < E) {
    int src = ei[e];
    int dst = ei[E + e];
    int p = atomicAdd(&cursor[dst], 1);
    csr[p] = src;
  }
}

// ---------------- f32 GEMM: [M,128] x [128,128], 64x64 tile, 4x4 reg tile ----
// Epilogue scales each output row by rs[row] (rs = dis): C = (A@B) * rs[row].
__global__ __launch_bounds__(256) void k_gemm(const float* __restrict__ A,
                                              const float* __restrict__ B,
                                              const float* __restrict__ rs,
                                              float* __restrict__ C, int M) {
  __shared__ float As[64][132];   // +4 pad: column reads spread over banks
  __shared__ float Bs[128][68];   // +4 keeps float4 rows 16B-aligned
  const int tid = threadIdx.x;
  const int rowBase = blockIdx.x * 64;
  const int colBase = blockIdx.y * 64;

  #pragma unroll
  for (int i = 0; i < 8; ++i) {           // A tile: 64 rows x 128 cols
    int f = tid + i * 256;                // 2048 float4
    int r = f >> 5;
    int c4 = (f & 31) << 2;
    int gr = rowBase + r;
    float4 v = make_float4(0.f, 0.f, 0.f, 0.f);
    if (gr < M) v = *reinterpret_cast<const float4*>(&A[(size_t)gr * CH + c4]);
    As[r][c4 + 0] = v.x; As[r][c4 + 1] = v.y; As[r][c4 + 2] = v.z; As[r][c4 + 3] = v.w;
  }
  #pragma unroll
  for (int i = 0; i < 8; ++i) {           // B tile: 128 k x 64 cols
    int f = tid + i * 256;
    int r = f >> 4;
    int c4 = (f & 15) << 2;
    float4 v = *reinterpret_cast<const float4*>(&B[r * CH + colBase + c4]);
    Bs[r][c4 + 0] = v.x; Bs[r][c4 + 1] = v.y; Bs[r][c4 + 2] = v.z; Bs[r][c4 + 3] = v.w;
  }
  __syncthreads();

  const int tx = tid & 15, ty = tid >> 4;
  const int r0 = ty * 4, c0 = tx * 4;
  float acc[4][4] = {};
  #pragma unroll 4
  for (int k = 0; k < 128; ++k) {
    float a0 = As[r0 + 0][k], a1 = As[r0 + 1][k], a2 = As[r0 + 2][k], a3 = As[r0 + 3][k];
    float4 b = *reinterpret_cast<const float4*>(&Bs[k][c0]);
    acc[0][0] += a0 * b.x; acc[0][1] += a0 * b.y; acc[0][2] += a0 * b.z; acc[0][3] += a0 * b.w;
    acc[1][0] += a1 * b.x; acc[1][1] += a1 * b.y; acc[1][2] += a1 * b.z; acc[1][3] += a1 * b.w;
    acc[2][0] += a2 * b.x; acc[2][1] += a2 * b.y; acc[2][2] += a2 * b.z; acc[2][3] += a2 * b.w;
    acc[3][0] += a3 * b.x; acc[3][1] += a3 * b.y; acc[3][2] += a3 * b.z; acc[3][3] += a3 * b.w;
  }
  #pragma unroll
  for (int i = 0; i < 4; ++i) {
    int gr = rowBase + r0 + i;
    if (gr < M) {
      const float s = rs[gr];
      float4 v = make_float4(acc[i][0] * s, acc[i][1] * s,
                             acc[i][2] * s, acc[i][3] * s);
      *reinterpret_cast<float4*>(&C[(size_t)gr * CH + colBase + c0]) = v;
    }
  }
}

// ---------------- aggregation: 1 wave per dst node, lane = 2 channels --------
// H is pre-scaled by dis[row] (H' = (A@W)*dis). Inner loop: pure adds,
// single dependent chain csr->H, 4 independent chains in flight.
template <int LAYER>
__global__ __launch_bounds__(256) void k_agg(const float* __restrict__ H,
                                             const int* __restrict__ offs,
                                             const int* __restrict__ csr,
                                             const float* __restrict__ dis,
                                             const float* __restrict__ bias,
                                             float* __restrict__ out, int n) {
  int wid = (blockIdx.x * 256 + threadIdx.x) >> 6;
  int lane = threadIdx.x & 63;
  if (wid >= n) return;
  const int row = wid;
  const float dd = dis[row];
  int e = offs[row];
  const int end = offs[row + 1];
  const int c = lane * 2;
  float ax0 = 0.f, ay0 = 0.f, ax1 = 0.f, ay1 = 0.f;
  float ax2 = 0.f, ay2 = 0.f, ax3 = 0.f, ay3 = 0.f;
  for (; e + 3 < end; e += 4) {           // 4 independent gather chains
    int s0 = csr[e], s1 = csr[e + 1], s2 = csr[e + 2], s3 = csr[e + 3];
    float2 v0 = *reinterpret_cast<const float2*>(&H[(size_t)s0 * CH + c]);
    float2 v1 = *reinterpret_cast<const float2*>(&H[(size_t)s1 * CH + c]);
    float2 v2 = *reinterpret_cast<const float2*>(&H[(size_t)s2 * CH + c]);
    float2 v3 = *reinterpret_cast<const float2*>(&H[(size_t)s3 * CH + c]);
    ax0 += v0.x; ay0 += v0.y;
    ax1 += v1.x; ay1 += v1.y;
    ax2 += v2.x; ay2 += v2.y;
    ax3 += v3.x; ay3 += v3.y;
  }
  for (; e < end; ++e) {
    int s0 = csr[e];
    float2 v0 = *reinterpret_cast<const float2*>(&H[(size_t)s0 * CH + c]);
    ax0 += v0.x; ay0 += v0.y;
  }
  float2 vs = *reinterpret_cast<const float2*>(&H[(size_t)row * CH + c]);
  // out = (sum_edges H' + H'[row]) * dd + bias
  float ax = ((ax0 + ax1) + (ax2 + ax3) + vs.x) * dd + bias[c];
  float ay = ((ay0 + ay1) + (ay2 + ay3) + vs.y) * dd + bias[c + 1];
  if (LAYER == 1) {
    ax = ax > 0.f ? ax : 0.01f * ax;      // leaky_relu(0.01)
    ay = ay > 0.f ? ay : 0.01f * ay;
    uint32_t i0 = (uint32_t)row * (uint32_t)CH + (uint32_t)c;
    ax = keep_mask(i0)      ? ax * (1.0f / 0.9f) : 0.0f;
    ay = keep_mask(i0 + 1u) ? ay * (1.0f / 0.9f) : 0.0f;
  }
  float2 o; o.x = ax; o.y = ay;
  *reinterpret_cast<float2*>(&out[(size_t)row * CH + c]) = o;
}

// ---------------- launch ----------------
extern "C" void kernel_launch(void* const* d_in, const int* in_sizes, int n_in,
                              void* d_out, int out_size, void* d_ws, size_t ws_size,
                              hipStream_t stream) {
  const float* x = (const float*)d_in[0];
  const int* ei = (const int*)d_in[1];   // int32 per harness contract, [2, E]
  const float* W1 = (const float*)d_in[2];
  const float* b1 = (const float*)d_in[3];
  const float* W2 = (const float*)d_in[4];
  const float* b2 = (const float*)d_in[5];
  float* out = (float*)d_out;

  const int N = in_sizes[0] / CH;     // 100000
  const int E = in_sizes[1] / 2;      // 1600000
  const int nb = (N + 1023) / 1024;   // scan blocks (98)

  // workspace carve-up (256B aligned), total ~59.2 MB
  char* ws = (char*)d_ws;
  size_t o = 0;
  auto take = [&](size_t bytes) -> void* {
    void* p = ws + o;
    o = (o + bytes + 255) & ~(size_t)255;
    return p;
  };
  int* cnt    = (int*)take((size_t)N * 4);
  int* offs   = (int*)take((size_t)(N + 1) * 4);
  int* cursor = (int*)take((size_t)N * 4);
  float* dis  = (float*)take((size_t)N * 4);
  int* csr    = (int*)take((size_t)E * 4);
  int* bsum   = (int*)take((size_t)nb * 4);
  int* bpre   = (int*)take((size_t)nb * 4);
  float* Hws  = (float*)take((size_t)N * CH * 4);

  hipMemsetAsync(cnt, 0, (size_t)N * 4, stream);

  const int eb = (E + 255) / 256;
  k_hist<<<eb, 256, 0, stream>>>(ei, cnt, E);
  k_scan1<<<nb, 256, 0, stream>>>(cnt, bsum, N);
  k_scan2<<<1, 128, 0, stream>>>(bsum, bpre, nb);
  k_scan3<<<nb, 256, 0, stream>>>(cnt, bpre, offs, cursor, dis, N, E);
  k_scatter<<<eb, 256, 0, stream>>>(ei, cursor, csr, E);

  dim3 gg((N + 63) / 64, CH / 64);
  const int ab = (N + 3) / 4;                               // 4 waves/block
  k_gemm<<<gg, 256, 0, stream>>>(x, W1, dis, Hws, N);       // Hws = (x@W1)*dis
  k_agg<1><<<ab, 256, 0, stream>>>(Hws, offs, csr, dis, b1, out, N);
  k_gemm<<<gg, 256, 0, stream>>>(out, W2, dis, Hws, N);     // Hws = (H2@W2)*dis
  k_agg<2><<<ab, 256, 0, stream>>>(Hws, offs, csr, dis, b2, out, N);
}